// Round 1
// baseline (289.385 us; speedup 1.0000x reference)
//
#include <hip/hip_runtime.h>
#include <math.h>

// tgate_hybrid: B=4,S=4096,DIMS=2048,T=10,K=2. Fused single kernel.
// Row-per-lane, 8 waves/block each owning a 256-wide d-slice, x staged
// through LDS for coalescing, W read via wave-uniform scalar loads.

#define NROWS   16384      // B*S
#define DIMS_   2048
#define TT      10
#define WAVES   8
#define BLOCK   (WAVES * 64)
#define DPW     (DIMS_ / WAVES)   // 256 d per wave
#define DC      16                // d-chunk per LDS stage
#define NCH     (DPW / DC)        // 16 chunks
#define PITCH   17                // LDS row pitch (pad: 2-way bank alias max = free)

__global__ __launch_bounds__(BLOCK)
void tgate_kernel(const float* __restrict__ x,
                  const float* __restrict__ W_cls,   const float* __restrict__ b_cls,
                  const float* __restrict__ W_sparse,const float* __restrict__ b_sparse,
                  const float* __restrict__ W_gates, const float* __restrict__ b_gates,
                  const float* __restrict__ alpha,
                  float* __restrict__ out)
{
    __shared__ float tile[WAVES * 64 * PITCH];   // 34816 B; reused for reduction

    const int tid  = threadIdx.x;
    const int lane = tid & 63;
    // force wave-uniform so W indexing becomes s_load (scalar pipe)
    const int wv   = __builtin_amdgcn_readfirstlane(tid >> 6);
    const int row0 = blockIdx.x * 64;
    const int d0b  = wv * DPW;
    float* tile_w  = &tile[wv * 64 * PITCH];

    float acc[30];
    #pragma unroll
    for (int j = 0; j < 30; ++j) acc[j] = 0.0f;

    const float4* x4 = reinterpret_cast<const float4*>(x);
    const int rl = lane >> 2;   // 0..15 : row-group within chunk load
    const int c4 = lane & 3;    // 0..3  : float4 column within 16-float chunk

    // prefetch chunk 0 (4 float4 per lane = 64 rows x 16 floats per wave)
    float4 pre[4];
    #pragma unroll
    for (int i = 0; i < 4; ++i) {
        int rr = i * 16 + rl;
        pre[i] = x4[(size_t)(row0 + rr) * (DIMS_ / 4) + (d0b >> 2) + c4];
    }

    for (int c = 0; c < NCH; ++c) {
        // stage prefetched chunk into this wave's private LDS region
        #pragma unroll
        for (int i = 0; i < 4; ++i) {
            int rr = i * 16 + rl;
            float* dst = tile_w + rr * PITCH + c4 * 4;
            dst[0] = pre[i].x; dst[1] = pre[i].y; dst[2] = pre[i].z; dst[3] = pre[i].w;
        }
        // prefetch next chunk (overlaps with compute below)
        if (c + 1 < NCH) {
            #pragma unroll
            for (int i = 0; i < 4; ++i) {
                int rr = i * 16 + rl;
                pre[i] = x4[(size_t)(row0 + rr) * (DIMS_ / 4) + ((d0b + (c + 1) * DC) >> 2) + c4];
            }
        }
        // compute: 16 d x 30 FMA; W loads are wave-uniform -> scalar pipe
        const int dg = d0b + c * DC;
        #pragma unroll
        for (int dd = 0; dd < DC; ++dd) {
            float xv = tile_w[lane * PITCH + dd];
            const float* wc = W_cls    + (size_t)(dg + dd) * TT;
            const float* ws = W_sparse + (size_t)(dg + dd) * TT;
            const float* wg = W_gates  + (size_t)(dg + dd) * TT;
            #pragma unroll
            for (int t = 0; t < TT; ++t) acc[t]      = fmaf(xv, wc[t], acc[t]);
            #pragma unroll
            for (int t = 0; t < TT; ++t) acc[10 + t] = fmaf(xv, ws[t], acc[10 + t]);
            #pragma unroll
            for (int t = 0; t < TT; ++t) acc[20 + t] = fmaf(xv, wg[t], acc[20 + t]);
        }
    }

    // cross-wave tree reduction of 30 partials (reuse tile as scratch)
    __syncthreads();
    float* part = tile;   // needs max 256*31 = 7936 floats <= 8704 available
    for (int half = WAVES / 2; half >= 1; half >>= 1) {
        if (wv >= half && wv < 2 * half) {
            float* p = part + ((size_t)((wv - half) * 64 + lane)) * 31;
            #pragma unroll
            for (int j = 0; j < 30; ++j) p[j] = acc[j];
        }
        __syncthreads();
        if (wv < half) {
            const float* p = part + ((size_t)(wv * 64 + lane)) * 31;
            #pragma unroll
            for (int j = 0; j < 30; ++j) acc[j] += p[j];
        }
        __syncthreads();
    }

    // epilogue: wave 0, one row per lane, all in registers
    if (wv == 0) {
        float lc[TT], lsp[TT], g[TT];
        #pragma unroll
        for (int t = 0; t < TT; ++t) {
            lc[t]  = acc[t]      + b_cls[t];
            lsp[t] = acc[10 + t] + b_sparse[t];
            float lg = acc[20 + t] + b_gates[t];
            g[t] = 1.0f / (1.0f + __expf(-lg));
        }
        // softmax(cls) dot gates
        float m = lc[0];
        #pragma unroll
        for (int t = 1; t < TT; ++t) m = fmaxf(m, lc[t]);
        float esum = 0.0f, gdot = 0.0f;
        #pragma unroll
        for (int t = 0; t < TT; ++t) {
            float e = __expf(lc[t] - m);
            esum += e;
            gdot = fmaf(g[t], e, gdot);
        }
        // branchless-carried top-2 over sparse logits (carry gate values, no dyn index)
        float v1 = lsp[0], v2 = -1e30f, gv1 = g[0], gv2 = 0.0f;
        #pragma unroll
        for (int t = 1; t < TT; ++t) {
            if (lsp[t] > v1)      { v2 = v1; gv2 = gv1; v1 = lsp[t]; gv1 = g[t]; }
            else if (lsp[t] > v2) { v2 = lsp[t]; gv2 = g[t]; }
        }
        float s1 = 1.0f / (1.0f + __expf(v2 - v1));   // softmax over top-2
        float s2 = 1.0f - s1;
        float a  = 1.0f / (1.0f + __expf(-alpha[0]));
        float sparse_dot = fmaf(gv1, s1, gv2 * s2);
        out[row0 + lane] = fmaf(a, sparse_dot, (1.0f - a) * (gdot / esum));
    }
}

extern "C" void kernel_launch(void* const* d_in, const int* in_sizes, int n_in,
                              void* d_out, int out_size, void* d_ws, size_t ws_size,
                              hipStream_t stream) {
    const float* x        = (const float*)d_in[0];
    const float* W_cls    = (const float*)d_in[1];
    const float* b_cls    = (const float*)d_in[2];
    const float* W_sparse = (const float*)d_in[3];
    const float* b_sparse = (const float*)d_in[4];
    const float* W_gates  = (const float*)d_in[5];
    const float* b_gates  = (const float*)d_in[6];
    const float* alpha    = (const float*)d_in[7];
    float* out = (float*)d_out;

    dim3 grid(NROWS / 64);     // 256 blocks, 1 per CU
    dim3 block(BLOCK);         // 512 threads = 8 waves
    tgate_kernel<<<grid, block, 0, stream>>>(x, W_cls, b_cls, W_sparse, b_sparse,
                                             W_gates, b_gates, alpha, out);
}

// Round 2
// 250.843 us; speedup vs baseline: 1.1537x; 1.1537x over previous
//
#include <hip/hip_runtime.h>
#include <math.h>

// tgate_hybrid: B=4,S=4096,DIMS=2048,T=10,K=2.
// K1: partial GEMV [64 rows x 64 d per wave], row-per-lane, x staged via LDS,
//     W via wave-uniform scalar loads; in-block 4-wave reduction -> ws partials.
// K2: thread-per-row 8-slice reduction + softmax/top2/sigmoid epilogue.

#define NROWS   16384
#define DIMS_   2048
#define TT      10
#define WAVES   4
#define BLOCK   (WAVES * 64)      // 256
#define DGRP    8                 // d-groups (grid.y)
#define DPW     (DIMS_ / DGRP / WAVES)   // 64 d per wave
#define DC      16                // d per staged chunk
#define NCH     (DPW / DC)        // 4 chunks
#define PITCH   17                // LDS pitch: conflict-free lane-major reads

__global__ __launch_bounds__(BLOCK)
void tgate_k1(const float* __restrict__ x,
              const float* __restrict__ W_cls,
              const float* __restrict__ W_sparse,
              const float* __restrict__ W_gates,
              float* __restrict__ ws)
{
    __shared__ float tile[WAVES * 64 * PITCH];   // 17408 B, reused for reduction

    const int tid  = threadIdx.x;
    const int lane = tid & 63;
    const int wv   = __builtin_amdgcn_readfirstlane(tid >> 6);
    const int row0 = blockIdx.x * 64;
    const int d0   = blockIdx.y * (DIMS_ / DGRP) + wv * DPW;
    float* tile_w  = &tile[wv * 64 * PITCH];

    float acc[30];
    #pragma unroll
    for (int j = 0; j < 30; ++j) acc[j] = 0.0f;

    const float4* x4 = reinterpret_cast<const float4*>(x);
    const int rl = lane >> 2;   // 0..15
    const int c4 = lane & 3;    // 0..3

    float4 pre[4];
    #pragma unroll
    for (int i = 0; i < 4; ++i) {
        int rr = i * 16 + rl;
        pre[i] = x4[(size_t)(row0 + rr) * (DIMS_ / 4) + (d0 >> 2) + c4];
    }

    for (int c = 0; c < NCH; ++c) {
        #pragma unroll
        for (int i = 0; i < 4; ++i) {
            int rr = i * 16 + rl;
            float* dst = tile_w + rr * PITCH + c4 * 4;
            dst[0] = pre[i].x; dst[1] = pre[i].y; dst[2] = pre[i].z; dst[3] = pre[i].w;
        }
        if (c + 1 < NCH) {
            #pragma unroll
            for (int i = 0; i < 4; ++i) {
                int rr = i * 16 + rl;
                pre[i] = x4[(size_t)(row0 + rr) * (DIMS_ / 4) + ((d0 + (c + 1) * DC) >> 2) + c4];
            }
        }
        const int dg = d0 + c * DC;
        #pragma unroll
        for (int dd = 0; dd < DC; ++dd) {
            float xv = tile_w[lane * PITCH + dd];
            const float* wc = W_cls    + (size_t)(dg + dd) * TT;
            const float* wsp= W_sparse + (size_t)(dg + dd) * TT;
            const float* wg = W_gates  + (size_t)(dg + dd) * TT;
            #pragma unroll
            for (int t = 0; t < TT; ++t) acc[t]      = fmaf(xv, wc[t],  acc[t]);
            #pragma unroll
            for (int t = 0; t < TT; ++t) acc[10 + t] = fmaf(xv, wsp[t], acc[10 + t]);
            #pragma unroll
            for (int t = 0; t < TT; ++t) acc[20 + t] = fmaf(xv, wg[t],  acc[20 + t]);
        }
    }

    // 4-wave tree reduction (pitch 31 -> conflict-free); 2 rounds fit in tile
    float* part = tile;
    __syncthreads();                       // all staging reads done
    if (wv >= 2) {
        float* p = part + (size_t)((wv - 2) * 64 + lane) * 31;
        #pragma unroll
        for (int j = 0; j < 30; ++j) p[j] = acc[j];
    }
    __syncthreads();
    if (wv < 2) {
        const float* p = part + (size_t)(wv * 64 + lane) * 31;
        #pragma unroll
        for (int j = 0; j < 30; ++j) acc[j] += p[j];
    }
    __syncthreads();
    if (wv == 1) {
        float* p = part + (size_t)lane * 31;
        #pragma unroll
        for (int j = 0; j < 30; ++j) p[j] = acc[j];
    }
    __syncthreads();
    if (wv == 0) {
        const float* p = part + (size_t)lane * 31;
        #pragma unroll
        for (int j = 0; j < 30; ++j) acc[j] += p[j];
        // write 64x32 partials: ws[(g*NROWS + row)*32 + t], float4 x8
        float4* w4 = reinterpret_cast<float4*>(ws);
        size_t base = ((size_t)blockIdx.y * NROWS + row0 + lane) * 8;
        #pragma unroll
        for (int q = 0; q < 8; ++q) {
            float a0 = (q * 4 + 0 < 30) ? acc[q * 4 + 0] : 0.0f;
            float a1 = (q * 4 + 1 < 30) ? acc[q * 4 + 1] : 0.0f;
            float a2 = (q * 4 + 2 < 30) ? acc[q * 4 + 2] : 0.0f;
            float a3 = (q * 4 + 3 < 30) ? acc[q * 4 + 3] : 0.0f;
            w4[base + q] = make_float4(a0, a1, a2, a3);
        }
    }
}

__global__ __launch_bounds__(256)
void tgate_k2(const float* __restrict__ ws,
              const float* __restrict__ b_cls,
              const float* __restrict__ b_sparse,
              const float* __restrict__ b_gates,
              const float* __restrict__ alpha,
              float* __restrict__ out)
{
    const int r = blockIdx.x * 256 + threadIdx.x;
    const float4* w4 = reinterpret_cast<const float4*>(ws);

    float l[32];
    #pragma unroll
    for (int j = 0; j < 32; ++j) l[j] = 0.0f;
    #pragma unroll
    for (int s = 0; s < DGRP; ++s) {
        size_t base = ((size_t)s * NROWS + r) * 8;
        #pragma unroll
        for (int q = 0; q < 8; ++q) {
            float4 v = w4[base + q];
            l[q * 4 + 0] += v.x; l[q * 4 + 1] += v.y;
            l[q * 4 + 2] += v.z; l[q * 4 + 3] += v.w;
        }
    }

    float lc[TT], lsp[TT], g[TT];
    #pragma unroll
    for (int t = 0; t < TT; ++t) {
        lc[t]  = l[t]      + b_cls[t];
        lsp[t] = l[10 + t] + b_sparse[t];
        float lg = l[20 + t] + b_gates[t];
        g[t] = 1.0f / (1.0f + __expf(-lg));
    }
    float m = lc[0];
    #pragma unroll
    for (int t = 1; t < TT; ++t) m = fmaxf(m, lc[t]);
    float esum = 0.0f, gdot = 0.0f;
    #pragma unroll
    for (int t = 0; t < TT; ++t) {
        float e = __expf(lc[t] - m);
        esum += e;
        gdot = fmaf(g[t], e, gdot);
    }
    float v1 = lsp[0], v2 = -1e30f, gv1 = g[0], gv2 = 0.0f;
    #pragma unroll
    for (int t = 1; t < TT; ++t) {
        if (lsp[t] > v1)      { v2 = v1; gv2 = gv1; v1 = lsp[t]; gv1 = g[t]; }
        else if (lsp[t] > v2) { v2 = lsp[t]; gv2 = g[t]; }
    }
    float s1 = 1.0f / (1.0f + __expf(v2 - v1));
    float s2 = 1.0f - s1;
    float a  = 1.0f / (1.0f + __expf(-alpha[0]));
    float sparse_dot = fmaf(gv1, s1, gv2 * s2);
    out[r] = fmaf(a, sparse_dot, (1.0f - a) * (gdot / esum));
}

extern "C" void kernel_launch(void* const* d_in, const int* in_sizes, int n_in,
                              void* d_out, int out_size, void* d_ws, size_t ws_size,
                              hipStream_t stream) {
    const float* x        = (const float*)d_in[0];
    const float* W_cls    = (const float*)d_in[1];
    const float* b_cls    = (const float*)d_in[2];
    const float* W_sparse = (const float*)d_in[3];
    const float* b_sparse = (const float*)d_in[4];
    const float* W_gates  = (const float*)d_in[5];
    const float* b_gates  = (const float*)d_in[6];
    const float* alpha    = (const float*)d_in[7];
    float* out = (float*)d_out;
    float* ws  = (float*)d_ws;   // needs DGRP*NROWS*32*4 = 16.8 MB

    dim3 g1(NROWS / 64, DGRP);   // 256 x 8 = 2048 blocks
    tgate_k1<<<g1, dim3(BLOCK), 0, stream>>>(x, W_cls, W_sparse, W_gates, ws);

    dim3 g2(NROWS / 256);        // 64 blocks
    tgate_k2<<<g2, dim3(256), 0, stream>>>(ws, b_cls, b_sparse, b_gates, alpha, out);
}

// Round 3
// 232.438 us; speedup vs baseline: 1.2450x; 1.0792x over previous
//
#include <hip/hip_runtime.h>
#include <math.h>

// tgate_hybrid: B=4,S=4096,DIMS=2048,T=10,K=2.
// K1: partial GEMV [64 rows x 64 d per wave], row-per-lane, x staged via LDS,
//     W preloaded into LDS (packed 32-float rows) -> broadcast ds_read_b128,
//     NO scalar loads in the hot loop (lgkmcnt chain fix).
// K2: thread-per-row 8-slice reduction + softmax/top2/sigmoid epilogue.

#define NROWS   16384
#define DIMS_   2048
#define TT      10
#define WAVES   4
#define BLOCK   (WAVES * 64)      // 256
#define DGRP    8                 // d-groups (grid.y)
#define DBLK    (DIMS_ / DGRP)    // 256 d per block
#define DPW     (DBLK / WAVES)    // 64 d per wave
#define DC      16                // d per staged chunk
#define NCH     (DPW / DC)        // 4 chunks
#define PITCH   17                // LDS pitch for x tile

__global__ __launch_bounds__(BLOCK)
void tgate_k1(const float* __restrict__ x,
              const float* __restrict__ W_cls,
              const float* __restrict__ W_sparse,
              const float* __restrict__ W_gates,
              float* __restrict__ ws)
{
    __shared__ float tile[WAVES * 64 * PITCH];   // 17408 B (x stage + reduction)
    __shared__ float Wlds[DBLK * 32];            // 32768 B: [d][cls0..9,sp0..9,g0..9,pad2]

    const int tid  = threadIdx.x;
    const int lane = tid & 63;
    const int wv   = __builtin_amdgcn_readfirstlane(tid >> 6);
    const int row0 = blockIdx.x * 64;
    const int dblk0 = blockIdx.y * DBLK;
    float* tile_w  = &tile[wv * 64 * PITCH];

    // ---- cooperative W preload: 3 matrices x 2560 floats, coalesced global reads
    {
        const float* Wm[3] = { W_cls, W_sparse, W_gates };
        #pragma unroll
        for (int m = 0; m < 3; ++m) {
            const float* src = Wm[m] + (size_t)dblk0 * TT;
            #pragma unroll
            for (int it = 0; it < DBLK * TT / BLOCK; ++it) {   // 10 iters
                int f = it * BLOCK + tid;        // 0..2559
                int d = f / TT, t = f - d * TT;
                Wlds[d * 32 + m * TT + t] = src[f];
            }
        }
    }

    float acc[30];
    #pragma unroll
    for (int j = 0; j < 30; ++j) acc[j] = 0.0f;

    const float4* x4 = reinterpret_cast<const float4*>(x);
    const int rl = lane >> 2;   // 0..15
    const int c4 = lane & 3;    // 0..3
    const int d0 = dblk0 + wv * DPW;

    float4 pre[4];
    #pragma unroll
    for (int i = 0; i < 4; ++i) {
        int rr = i * 16 + rl;
        pre[i] = x4[(size_t)(row0 + rr) * (DIMS_ / 4) + (d0 >> 2) + c4];
    }

    __syncthreads();   // Wlds ready before any wave reads it

    for (int c = 0; c < NCH; ++c) {
        #pragma unroll
        for (int i = 0; i < 4; ++i) {
            int rr = i * 16 + rl;
            float* dst = tile_w + rr * PITCH + c4 * 4;
            dst[0] = pre[i].x; dst[1] = pre[i].y; dst[2] = pre[i].z; dst[3] = pre[i].w;
        }
        if (c + 1 < NCH) {
            #pragma unroll
            for (int i = 0; i < 4; ++i) {
                int rr = i * 16 + rl;
                pre[i] = x4[(size_t)(row0 + rr) * (DIMS_ / 4) + ((d0 + (c + 1) * DC) >> 2) + c4];
            }
        }
        const int dloc0 = wv * DPW + c * DC;   // block-local d of this chunk
        #pragma unroll
        for (int dd = 0; dd < DC; ++dd) {
            float xv = tile_w[lane * PITCH + dd];
            const float4* wrow = reinterpret_cast<const float4*>(&Wlds[(dloc0 + dd) * 32]);
            float4 w0 = wrow[0], w1 = wrow[1], w2 = wrow[2], w3 = wrow[3];
            float4 w4 = wrow[4], w5 = wrow[5], w6 = wrow[6], w7 = wrow[7];
            acc[ 0] = fmaf(xv, w0.x, acc[ 0]); acc[ 1] = fmaf(xv, w0.y, acc[ 1]);
            acc[ 2] = fmaf(xv, w0.z, acc[ 2]); acc[ 3] = fmaf(xv, w0.w, acc[ 3]);
            acc[ 4] = fmaf(xv, w1.x, acc[ 4]); acc[ 5] = fmaf(xv, w1.y, acc[ 5]);
            acc[ 6] = fmaf(xv, w1.z, acc[ 6]); acc[ 7] = fmaf(xv, w1.w, acc[ 7]);
            acc[ 8] = fmaf(xv, w2.x, acc[ 8]); acc[ 9] = fmaf(xv, w2.y, acc[ 9]);
            acc[10] = fmaf(xv, w2.z, acc[10]); acc[11] = fmaf(xv, w2.w, acc[11]);
            acc[12] = fmaf(xv, w3.x, acc[12]); acc[13] = fmaf(xv, w3.y, acc[13]);
            acc[14] = fmaf(xv, w3.z, acc[14]); acc[15] = fmaf(xv, w3.w, acc[15]);
            acc[16] = fmaf(xv, w4.x, acc[16]); acc[17] = fmaf(xv, w4.y, acc[17]);
            acc[18] = fmaf(xv, w4.z, acc[18]); acc[19] = fmaf(xv, w4.w, acc[19]);
            acc[20] = fmaf(xv, w5.x, acc[20]); acc[21] = fmaf(xv, w5.y, acc[21]);
            acc[22] = fmaf(xv, w5.z, acc[22]); acc[23] = fmaf(xv, w5.w, acc[23]);
            acc[24] = fmaf(xv, w6.x, acc[24]); acc[25] = fmaf(xv, w6.y, acc[25]);
            acc[26] = fmaf(xv, w6.z, acc[26]); acc[27] = fmaf(xv, w6.w, acc[27]);
            acc[28] = fmaf(xv, w7.x, acc[28]); acc[29] = fmaf(xv, w7.y, acc[29]);
        }
    }

    // 4-wave tree reduction (reuse tile; pitch 31 conflict-free)
    float* part = tile;
    __syncthreads();
    if (wv >= 2) {
        float* p = part + (size_t)((wv - 2) * 64 + lane) * 31;
        #pragma unroll
        for (int j = 0; j < 30; ++j) p[j] = acc[j];
    }
    __syncthreads();
    if (wv < 2) {
        const float* p = part + (size_t)(wv * 64 + lane) * 31;
        #pragma unroll
        for (int j = 0; j < 30; ++j) acc[j] += p[j];
    }
    __syncthreads();
    if (wv == 1) {
        float* p = part + (size_t)lane * 31;
        #pragma unroll
        for (int j = 0; j < 30; ++j) p[j] = acc[j];
    }
    __syncthreads();
    if (wv == 0) {
        const float* p = part + (size_t)lane * 31;
        #pragma unroll
        for (int j = 0; j < 30; ++j) acc[j] += p[j];
        float4* w4p = reinterpret_cast<float4*>(ws);
        size_t base = ((size_t)blockIdx.y * NROWS + row0 + lane) * 8;
        #pragma unroll
        for (int q = 0; q < 8; ++q) {
            float a0 = (q * 4 + 0 < 30) ? acc[q * 4 + 0] : 0.0f;
            float a1 = (q * 4 + 1 < 30) ? acc[q * 4 + 1] : 0.0f;
            float a2 = (q * 4 + 2 < 30) ? acc[q * 4 + 2] : 0.0f;
            float a3 = (q * 4 + 3 < 30) ? acc[q * 4 + 3] : 0.0f;
            w4p[base + q] = make_float4(a0, a1, a2, a3);
        }
    }
}

__global__ __launch_bounds__(256)
void tgate_k2(const float* __restrict__ ws,
              const float* __restrict__ b_cls,
              const float* __restrict__ b_sparse,
              const float* __restrict__ b_gates,
              const float* __restrict__ alpha,
              float* __restrict__ out)
{
    const int r = blockIdx.x * 256 + threadIdx.x;
    const float4* w4 = reinterpret_cast<const float4*>(ws);

    float l[32];
    #pragma unroll
    for (int j = 0; j < 32; ++j) l[j] = 0.0f;
    #pragma unroll
    for (int s = 0; s < DGRP; ++s) {
        size_t base = ((size_t)s * NROWS + r) * 8;
        #pragma unroll
        for (int q = 0; q < 8; ++q) {
            float4 v = w4[base + q];
            l[q * 4 + 0] += v.x; l[q * 4 + 1] += v.y;
            l[q * 4 + 2] += v.z; l[q * 4 + 3] += v.w;
        }
    }

    float lc[TT], lsp[TT], g[TT];
    #pragma unroll
    for (int t = 0; t < TT; ++t) {
        lc[t]  = l[t]      + b_cls[t];
        lsp[t] = l[10 + t] + b_sparse[t];
        float lg = l[20 + t] + b_gates[t];
        g[t] = 1.0f / (1.0f + __expf(-lg));
    }
    float m = lc[0];
    #pragma unroll
    for (int t = 1; t < TT; ++t) m = fmaxf(m, lc[t]);
    float esum = 0.0f, gdot = 0.0f;
    #pragma unroll
    for (int t = 0; t < TT; ++t) {
        float e = __expf(lc[t] - m);
        esum += e;
        gdot = fmaf(g[t], e, gdot);
    }
    float v1 = lsp[0], v2 = -1e30f, gv1 = g[0], gv2 = 0.0f;
    #pragma unroll
    for (int t = 1; t < TT; ++t) {
        if (lsp[t] > v1)      { v2 = v1; gv2 = gv1; v1 = lsp[t]; gv1 = g[t]; }
        else if (lsp[t] > v2) { v2 = lsp[t]; gv2 = g[t]; }
    }
    float s1 = 1.0f / (1.0f + __expf(v2 - v1));
    float s2 = 1.0f - s1;
    float a  = 1.0f / (1.0f + __expf(-alpha[0]));
    float sparse_dot = fmaf(gv1, s1, gv2 * s2);
    out[r] = fmaf(a, sparse_dot, (1.0f - a) * (gdot / esum));
}

extern "C" void kernel_launch(void* const* d_in, const int* in_sizes, int n_in,
                              void* d_out, int out_size, void* d_ws, size_t ws_size,
                              hipStream_t stream) {
    const float* x        = (const float*)d_in[0];
    const float* W_cls    = (const float*)d_in[1];
    const float* b_cls    = (const float*)d_in[2];
    const float* W_sparse = (const float*)d_in[3];
    const float* b_sparse = (const float*)d_in[4];
    const float* W_gates  = (const float*)d_in[5];
    const float* b_gates  = (const float*)d_in[6];
    const float* alpha    = (const float*)d_in[7];
    float* out = (float*)d_out;
    float* ws  = (float*)d_ws;   // DGRP*NROWS*32*4 = 16.8 MB

    dim3 g1(NROWS / 64, DGRP);   // 2048 blocks
    tgate_k1<<<g1, dim3(BLOCK), 0, stream>>>(x, W_cls, W_sparse, W_gates, ws);

    dim3 g2(NROWS / 256);        // 64 blocks
    tgate_k2<<<g2, dim3(256), 0, stream>>>(ws, b_cls, b_sparse, b_gates, alpha, out);
}